// Round 3
// baseline (2903.318 us; speedup 1.0000x reference)
//
#include <hip/hip_runtime.h>
#include <stdint.h>

#define LN_EPS 1e-5f

// LayerNorm(C) + ReLU over a register array. All loops fully unrolled so the
// array stays in VGPRs (compile-time indices only).
template <int C>
__device__ __forceinline__ void ln_relu(float (&a)[C], const float* __restrict__ g,
                                        const float* __restrict__ b, float inv_c) {
  float p0 = 0.f, p1 = 0.f, p2 = 0.f, p3 = 0.f;
#pragma unroll
  for (int j = 0; j < C; j += 4) { p0 += a[j]; p1 += a[j + 1]; p2 += a[j + 2]; p3 += a[j + 3]; }
  float mu = ((p0 + p1) + (p2 + p3)) * inv_c;
  float q0 = 0.f, q1 = 0.f, q2 = 0.f, q3 = 0.f;
#pragma unroll
  for (int j = 0; j < C; j += 4) {
    float d0 = a[j] - mu, d1 = a[j + 1] - mu, d2 = a[j + 2] - mu, d3 = a[j + 3] - mu;
    a[j] = d0; a[j + 1] = d1; a[j + 2] = d2; a[j + 3] = d3;
    q0 = fmaf(d0, d0, q0); q1 = fmaf(d1, d1, q1); q2 = fmaf(d2, d2, q2); q3 = fmaf(d3, d3, q3);
  }
  float var = ((q0 + q1) + (q2 + q3)) * inv_c;
  float rs = rsqrtf(var + LN_EPS);
#pragma unroll
  for (int j = 0; j < C; ++j) {
    float t = a[j] * rs;
    t = fmaf(t, g[j], b[j]);
    a[j] = fmaxf(t, 0.f);
  }
}

// R4: identical structure to R3 (2 rows/thread), ONLY the launch bounds changed.
// R3 post-mortem (measured): __launch_bounds__(256,4) capped the allocator at
// 64 VGPRs (rocprof VGPR_Count=64) against a ~110-reg live set -> heavy scratch
// spill. Evidence: WRITE_SIZE 227MB vs 16.4MB ideal (14x over-write = spill
// round-trips), FETCH 657MB vs 366MB ideal, VALU-busy time 580us vs ~50us of
// useful work (spill-code bloat), occupancy capped at 43% by scratch.
// Fix: __launch_bounds__(256) (min-waves defaults to 1) lifts the VGPR cap;
// ~115 live regs fit with zero spill at an expected 4 waves/SIMD.
__global__ __launch_bounds__(256) void dec_kernel(
    const float* __restrict__ x,
    const float* __restrict__ w1, const float* __restrict__ g1, const float* __restrict__ b1,
    const float* __restrict__ w2, const float* __restrict__ g2, const float* __restrict__ b2,
    const float* __restrict__ w3, const float* __restrict__ b3,
    float* __restrict__ out, int N, int HW)
{
  const int t  = threadIdx.x;
  const int r0 = blockIdx.x * 512 + t;
  if (r0 >= N) return;
  const int r1   = r0 + 256;
  const bool has1 = (r1 < N);
  const int r1c  = has1 ? r1 : r0;   // clamp: duplicate work, store discarded

  const float4* __restrict__ xp0 = (const float4*)(x + (size_t)r0  * 64);
  const float4* __restrict__ xp1 = (const float4*)(x + (size_t)r1c * 64);

  // ---- layer 1: K=64 -> 32, two rows ----
  float acc0[32], acc1[32];
#pragma unroll
  for (int j = 0; j < 32; ++j) { acc0[j] = 0.f; acc1[j] = 0.f; }

#pragma unroll
  for (int c = 0; c < 4; ++c) {
    float4 xa[4], xb[4];
#pragma unroll
    for (int q = 0; q < 4; ++q) { xa[q] = xp0[c * 4 + q]; xb[q] = xp1[c * 4 + q]; }
#pragma unroll
    for (int q = 0; q < 4; ++q) {
#pragma unroll
      for (int kk = 0; kk < 4; ++kk) {
        const int k = c * 16 + q * 4 + kk;
        const float xk0 = (kk == 0) ? xa[q].x : (kk == 1) ? xa[q].y : (kk == 2) ? xa[q].z : xa[q].w;
        const float xk1 = (kk == 0) ? xb[q].x : (kk == 1) ? xb[q].y : (kk == 2) ? xb[q].z : xb[q].w;
        const float* __restrict__ wrow = w1 + k * 32;   // wave-uniform -> s_load
#pragma unroll
        for (int j = 0; j < 32; ++j) {
          const float w = wrow[j];                      // one SGPR, feeds 2 FMAs
          acc0[j] = fmaf(xk0, w, acc0[j]);
          acc1[j] = fmaf(xk1, w, acc1[j]);
        }
      }
    }
  }

  ln_relu<32>(acc0, g1, b1, 0.03125f);
  ln_relu<32>(acc1, g1, b1, 0.03125f);

  // ---- layer 2: K=32 -> 16, two rows ----
  float a20[16], a21[16];
#pragma unroll
  for (int j = 0; j < 16; ++j) { a20[j] = 0.f; a21[j] = 0.f; }
#pragma unroll
  for (int k = 0; k < 32; ++k) {
    const float h0 = acc0[k], h1 = acc1[k];
    const float* __restrict__ wrow = w2 + k * 16;       // wave-uniform -> s_load
#pragma unroll
    for (int j = 0; j < 16; ++j) {
      const float w = wrow[j];
      a20[j] = fmaf(h0, w, a20[j]);
      a21[j] = fmaf(h1, w, a21[j]);
    }
  }

  ln_relu<16>(a20, g2, b2, 0.0625f);
  ln_relu<16>(a21, g2, b2, 0.0625f);

  // ---- layer 3 + channel L2-normalize, two rows ----
  float o00 = b3[0], o01 = b3[1], o02 = b3[2];
  float o10 = b3[0], o11 = b3[1], o12 = b3[2];
#pragma unroll
  for (int k = 0; k < 16; ++k) {
    const float wa = w3[k * 3 + 0], wb = w3[k * 3 + 1], wc = w3[k * 3 + 2];
    o00 = fmaf(a20[k], wa, o00); o01 = fmaf(a20[k], wb, o01); o02 = fmaf(a20[k], wc, o02);
    o10 = fmaf(a21[k], wa, o10); o11 = fmaf(a21[k], wb, o11); o12 = fmaf(a21[k], wc, o12);
  }

  {
    float nsq = fmaf(o00, o00, fmaf(o01, o01, o02 * o02));
    float inv = rsqrtf(fmaxf(nsq, 1e-24f));   // == 1/max(||o||,1e-12)
    o00 *= inv; o01 *= inv; o02 *= inv;
  }
  {
    float nsq = fmaf(o10, o10, fmaf(o11, o11, o12 * o12));
    float inv = rsqrtf(fmaxf(nsq, 1e-24f));
    o10 *= inv; o11 *= inv; o12 *= inv;
  }

  // out[b][c][h][w]; flat = b*3*HW + c*HW + p; lanes consecutive in p -> coalesced
  {
    const unsigned b0 = (unsigned)r0 / (unsigned)HW;
    const unsigned p0 = (unsigned)r0 - b0 * (unsigned)HW;
    const size_t ob = (size_t)b0 * 3 * HW + p0;
    out[ob] = o00; out[ob + HW] = o01; out[ob + 2 * HW] = o02;
  }
  if (has1) {
    const unsigned b1i = (unsigned)r1 / (unsigned)HW;
    const unsigned p1  = (unsigned)r1 - b1i * (unsigned)HW;
    const size_t ob = (size_t)b1i * 3 * HW + p1;
    out[ob] = o10; out[ob + HW] = o11; out[ob + 2 * HW] = o12;
  }
}

extern "C" void kernel_launch(void* const* d_in, const int* in_sizes, int n_in,
                              void* d_out, int out_size, void* d_ws, size_t ws_size,
                              hipStream_t stream) {
  const float* x  = (const float*)d_in[0];
  const float* w1 = (const float*)d_in[1];
  const float* g1 = (const float*)d_in[2];
  const float* b1 = (const float*)d_in[3];
  const float* w2 = (const float*)d_in[4];
  const float* g2 = (const float*)d_in[5];
  const float* b2 = (const float*)d_in[6];
  const float* w3 = (const float*)d_in[7];
  const float* b3 = (const float*)d_in[8];
  float* out = (float*)d_out;

  const int N  = in_sizes[0] / 64;  // rows
  const int HW = N / 4;             // B = 4 per reference setup
  const int nblocks = (N + 511) / 512;   // 512 rows per block (2 per thread)
  dec_kernel<<<nblocks, 256, 0, stream>>>(x, w1, g1, b1, w2, g2, b2, w3, b3, out, N, HW);
}

// Round 4
// 523.848 us; speedup vs baseline: 5.5423x; 5.5423x over previous
//
#include <hip/hip_runtime.h>
#include <stdint.h>

#define LN_EPS 1e-5f

// LayerNorm(C) + ReLU over a register array. Fully unrolled (reg arrays need
// compile-time indices).
template <int C>
__device__ __forceinline__ void ln_relu(float (&a)[C], const float* __restrict__ g,
                                        const float* __restrict__ b, float inv_c) {
  float p0 = 0.f, p1 = 0.f, p2 = 0.f, p3 = 0.f;
#pragma unroll
  for (int j = 0; j < C; j += 4) { p0 += a[j]; p1 += a[j + 1]; p2 += a[j + 2]; p3 += a[j + 3]; }
  float mu = ((p0 + p1) + (p2 + p3)) * inv_c;
  float q0 = 0.f, q1 = 0.f, q2 = 0.f, q3 = 0.f;
#pragma unroll
  for (int j = 0; j < C; j += 4) {
    float d0 = a[j] - mu, d1 = a[j + 1] - mu, d2 = a[j + 2] - mu, d3 = a[j + 3] - mu;
    a[j] = d0; a[j + 1] = d1; a[j + 2] = d2; a[j + 3] = d3;
    q0 = fmaf(d0, d0, q0); q1 = fmaf(d1, d1, q1); q2 = fmaf(d2, d2, q2); q3 = fmaf(d3, d3, q3);
  }
  float var = ((q0 + q1) + (q2 + q3)) * inv_c;
  float rs = rsqrtf(var + LN_EPS);
#pragma unroll
  for (int j = 0; j < C; ++j) {
    float t = a[j] * rs;
    t = fmaf(t, g[j], b[j]);
    a[j] = fmaxf(t, 0.f);
  }
}

// R5: back to 1 row/thread; code made SMALL (rolled layer-1 chunk loop) and
// VGPR budget ~64 for 7-8 waves/SIMD.
// R4 post-mortem (measured): no-spill 2-row kernel was LATENCY-bound, not
// spill-bound: HBM 1.0%, VALUBusy 19%, occupancy 21.5%, ~80% of cycles idle.
// Causes: (a) fully-unrolled ~80KB straight-line I-stream — zero I$ reuse,
// every wave streams code from L2; (b) 2 rows/thread halved wave count and
// 104 VGPRs capped 4 waves/SIMD. Occupancy, not weight-dwords/FMA, tracked
// runtime across R2(43%/1834as-spilled... prev 575)/R3(43%/1834)/R4(21.5%/2540).
// Fix: hot loop ~4.5KB reused 4x (I$-resident), 2x wave count, VGPR ~64-70.
// Weight rows stay wave-uniform -> s_load, now pipelineable inside a loop,
// with 7-8 waves/SIMD to hide K$ latency.
// x loads: one 64B line per lane per chunk, consumed by 4 back-to-back
// dwordx4 (keeps the over-fetch fix: FETCH stays ~1x of x).
__global__ __launch_bounds__(256) void dec_kernel(
    const float* __restrict__ x,
    const float* __restrict__ w1, const float* __restrict__ g1, const float* __restrict__ b1,
    const float* __restrict__ w2, const float* __restrict__ g2, const float* __restrict__ b2,
    const float* __restrict__ w3, const float* __restrict__ b3,
    float* __restrict__ out, int N, int HW)
{
  const int row = blockIdx.x * 256 + threadIdx.x;
  if (row >= N) return;

  const float4* __restrict__ xp = (const float4*)(x + (size_t)row * 64);

  // ---- layer 1: K=64 -> 32, rolled over 4 chunks of 16 ----
  float acc[32];
#pragma unroll
  for (int j = 0; j < 32; ++j) acc[j] = 0.f;

#pragma unroll 1
  for (int c = 0; c < 4; ++c) {
    const float4 x0 = xp[c * 4 + 0];
    const float4 x1 = xp[c * 4 + 1];
    const float4 x2 = xp[c * 4 + 2];
    const float4 x3 = xp[c * 4 + 3];
    const float* __restrict__ wbase = w1 + c * 16 * 32;
#pragma unroll
    for (int q = 0; q < 4; ++q) {
      const float4 xq = (q == 0) ? x0 : (q == 1) ? x1 : (q == 2) ? x2 : x3;
#pragma unroll
      for (int kk = 0; kk < 4; ++kk) {
        const float xk = (kk == 0) ? xq.x : (kk == 1) ? xq.y : (kk == 2) ? xq.z : xq.w;
        const float* __restrict__ wrow = wbase + (q * 4 + kk) * 32;  // uniform -> s_load
#pragma unroll
        for (int j = 0; j < 32; ++j) acc[j] = fmaf(xk, wrow[j], acc[j]);
      }
    }
  }

  ln_relu<32>(acc, g1, b1, 0.03125f);

  // ---- layer 2: K=32 -> 16 (acc[k] needs compile-time k -> full unroll) ----
  float a2[16];
#pragma unroll
  for (int j = 0; j < 16; ++j) a2[j] = 0.f;
#pragma unroll
  for (int k = 0; k < 32; ++k) {
    const float hk = acc[k];
    const float* __restrict__ wrow = w2 + k * 16;        // uniform -> s_load
#pragma unroll
    for (int j = 0; j < 16; ++j) a2[j] = fmaf(hk, wrow[j], a2[j]);
  }

  ln_relu<16>(a2, g2, b2, 0.0625f);

  // ---- layer 3 + channel L2-normalize ----
  float o0 = b3[0], o1 = b3[1], o2 = b3[2];
#pragma unroll
  for (int k = 0; k < 16; ++k) {
    const float hk = a2[k];
    o0 = fmaf(hk, w3[k * 3 + 0], o0);
    o1 = fmaf(hk, w3[k * 3 + 1], o1);
    o2 = fmaf(hk, w3[k * 3 + 2], o2);
  }
  const float nsq = fmaf(o0, o0, fmaf(o1, o1, o2 * o2));
  const float inv = rsqrtf(fmaxf(nsq, 1e-24f));  // == 1/max(||o||,1e-12)
  o0 *= inv; o1 *= inv; o2 *= inv;

  // out[b][c][h][w]; flat = b*3*HW + c*HW + p; lanes consecutive in p -> coalesced
  const unsigned b = (unsigned)row / (unsigned)HW;
  const unsigned p = (unsigned)row - b * (unsigned)HW;
  const size_t obase = (size_t)b * 3 * HW + p;
  out[obase]          = o0;
  out[obase + HW]     = o1;
  out[obase + 2 * HW] = o2;
}

extern "C" void kernel_launch(void* const* d_in, const int* in_sizes, int n_in,
                              void* d_out, int out_size, void* d_ws, size_t ws_size,
                              hipStream_t stream) {
  const float* x  = (const float*)d_in[0];
  const float* w1 = (const float*)d_in[1];
  const float* g1 = (const float*)d_in[2];
  const float* b1 = (const float*)d_in[3];
  const float* w2 = (const float*)d_in[4];
  const float* g2 = (const float*)d_in[5];
  const float* b2 = (const float*)d_in[6];
  const float* w3 = (const float*)d_in[7];
  const float* b3 = (const float*)d_in[8];
  float* out = (float*)d_out;

  const int N  = in_sizes[0] / 64;  // rows
  const int HW = N / 4;             // B = 4 per reference setup
  const int nblocks = (N + 255) / 256;
  dec_kernel<<<nblocks, 256, 0, stream>>>(x, w1, g1, b1, w2, g2, b2, w3, b3, out, N, HW);
}

// Round 6
// 512.034 us; speedup vs baseline: 5.6702x; 1.0231x over previous
//
#include <hip/hip_runtime.h>
#include <stdint.h>

#define LN_EPS 1e-5f

// LayerNorm(C) + ReLU over a register array. Fully unrolled (reg arrays need
// compile-time indices).
template <int C>
__device__ __forceinline__ void ln_relu(float (&a)[C], const float* __restrict__ g,
                                        const float* __restrict__ b, float inv_c) {
  float p0 = 0.f, p1 = 0.f, p2 = 0.f, p3 = 0.f;
#pragma unroll
  for (int j = 0; j < C; j += 4) { p0 += a[j]; p1 += a[j + 1]; p2 += a[j + 2]; p3 += a[j + 3]; }
  float mu = ((p0 + p1) + (p2 + p3)) * inv_c;
  float q0 = 0.f, q1 = 0.f, q2 = 0.f, q3 = 0.f;
#pragma unroll
  for (int j = 0; j < C; j += 4) {
    float d0 = a[j] - mu, d1 = a[j + 1] - mu, d2 = a[j + 2] - mu, d3 = a[j + 3] - mu;
    a[j] = d0; a[j + 1] = d1; a[j + 2] = d2; a[j + 3] = d3;
    q0 = fmaf(d0, d0, q0); q1 = fmaf(d1, d1, q1); q2 = fmaf(d2, d2, q2); q3 = fmaf(d3, d3, q3);
  }
  float var = ((q0 + q1) + (q2 + q3)) * inv_c;
  float rs = rsqrtf(var + LN_EPS);
#pragma unroll
  for (int j = 0; j < C; ++j) {
    float t = a[j] * rs;
    t = fmaf(t, g[j], b[j]);
    a[j] = fmaxf(t, 0.f);
  }
}

// R6 (unmeasured -- GPU acquisition timed out; resubmitted verbatim).
// R5 + distance-1 software prefetch of the next x-line in the rolled
// layer-1 loop (single-variable change vs the measured R5 = ~170us kernel).
// R5 post-mortem: bench 2903->524us; dec_kernel dropped below the 212us
// harness fill kernels in the profile => kernel ~170us. Still ~3.4x the
// 48us VALU-issue floor => latency-bound. Theory: each chunk issues its 4
// x-line dwordx4 loads immediately before their first use, exposing one
// full L2/HBM latency per chunk against 1024cyc of FMA issue, with only
// ~4 waves/SIMD of cover.
// Fix: load chunk c+1's line before chunk c's FMA block; register swap at
// bottom (compile-time names only -> no scratch). Compiler should emit
// vmcnt(4)-style waits: chunk c waits on loads issued a full chunk earlier.
// Cost +16 VGPR (~85). If this regresses via a VGPR occupancy cliff,
// revert to R5-slim next round.
__global__ __launch_bounds__(256) void dec_kernel(
    const float* __restrict__ x,
    const float* __restrict__ w1, const float* __restrict__ g1, const float* __restrict__ b1,
    const float* __restrict__ w2, const float* __restrict__ g2, const float* __restrict__ b2,
    const float* __restrict__ w3, const float* __restrict__ b3,
    float* __restrict__ out, int N, int HW)
{
  const int row = blockIdx.x * 256 + threadIdx.x;
  if (row >= N) return;

  const float4* __restrict__ xp = (const float4*)(x + (size_t)row * 64);

  // ---- layer 1: K=64 -> 32, rolled over 4 chunks of 16, dist-1 prefetch ----
  float acc[32];
#pragma unroll
  for (int j = 0; j < 32; ++j) acc[j] = 0.f;

  // prologue: line 0
  float4 c0 = xp[0], c1 = xp[1], c2 = xp[2], c3 = xp[3];

#pragma unroll 1
  for (int c = 0; c < 4; ++c) {
    // prefetch next line (clamped on last iter -> L1-hot reload, branch-free)
    const int nc = (c < 3) ? (c + 1) : 3;
    float4 n0 = xp[nc * 4 + 0];
    float4 n1 = xp[nc * 4 + 1];
    float4 n2 = xp[nc * 4 + 2];
    float4 n3 = xp[nc * 4 + 3];

    const float* __restrict__ wbase = w1 + c * 16 * 32;
#pragma unroll
    for (int q = 0; q < 4; ++q) {
      const float4 xq = (q == 0) ? c0 : (q == 1) ? c1 : (q == 2) ? c2 : c3;
#pragma unroll
      for (int kk = 0; kk < 4; ++kk) {
        const float xk = (kk == 0) ? xq.x : (kk == 1) ? xq.y : (kk == 2) ? xq.z : xq.w;
        const float* __restrict__ wrow = wbase + (q * 4 + kk) * 32;  // uniform -> s_load
#pragma unroll
        for (int j = 0; j < 32; ++j) acc[j] = fmaf(xk, wrow[j], acc[j]);
      }
    }
    c0 = n0; c1 = n1; c2 = n2; c3 = n3;
  }

  ln_relu<32>(acc, g1, b1, 0.03125f);

  // ---- layer 2: K=32 -> 16 (acc[k] needs compile-time k -> full unroll) ----
  float a2[16];
#pragma unroll
  for (int j = 0; j < 16; ++j) a2[j] = 0.f;
#pragma unroll
  for (int k = 0; k < 32; ++k) {
    const float hk = acc[k];
    const float* __restrict__ wrow = w2 + k * 16;        // uniform -> s_load
#pragma unroll
    for (int j = 0; j < 16; ++j) a2[j] = fmaf(hk, wrow[j], a2[j]);
  }

  ln_relu<16>(a2, g2, b2, 0.0625f);

  // ---- layer 3 + channel L2-normalize ----
  float o0 = b3[0], o1 = b3[1], o2 = b3[2];
#pragma unroll
  for (int k = 0; k < 16; ++k) {
    const float hk = a2[k];
    o0 = fmaf(hk, w3[k * 3 + 0], o0);
    o1 = fmaf(hk, w3[k * 3 + 1], o1);
    o2 = fmaf(hk, w3[k * 3 + 2], o2);
  }
  const float nsq = fmaf(o0, o0, fmaf(o1, o1, o2 * o2));
  const float inv = rsqrtf(fmaxf(nsq, 1e-24f));  // == 1/max(||o||,1e-12)
  o0 *= inv; o1 *= inv; o2 *= inv;

  // out[b][c][h][w]; flat = b*3*HW + c*HW + p; lanes consecutive in p -> coalesced
  const unsigned b = (unsigned)row / (unsigned)HW;
  const unsigned p = (unsigned)row - b * (unsigned)HW;
  const size_t obase = (size_t)b * 3 * HW + p;
  out[obase]          = o0;
  out[obase + HW]     = o1;
  out[obase + 2 * HW] = o2;
}

extern "C" void kernel_launch(void* const* d_in, const int* in_sizes, int n_in,
                              void* d_out, int out_size, void* d_ws, size_t ws_size,
                              hipStream_t stream) {
  const float* x  = (const float*)d_in[0];
  const float* w1 = (const float*)d_in[1];
  const float* g1 = (const float*)d_in[2];
  const float* b1 = (const float*)d_in[3];
  const float* w2 = (const float*)d_in[4];
  const float* g2 = (const float*)d_in[5];
  const float* b2 = (const float*)d_in[6];
  const float* w3 = (const float*)d_in[7];
  const float* b3 = (const float*)d_in[8];
  float* out = (float*)d_out;

  const int N  = in_sizes[0] / 64;  // rows
  const int HW = N / 4;             // B = 4 per reference setup
  const int nblocks = (N + 255) / 256;
  dec_kernel<<<nblocks, 256, 0, stream>>>(x, w1, g1, b1, w2, g2, b2, w3, b3, out, N, HW);
}